// Round 8
// baseline (218.181 us; speedup 1.0000x reference)
//
#include <hip/hip_runtime.h>

#define S_LEN 2048
#define BATCH_N 2
#define DM 512
#define H_N 8
#define DK_N 64
#define FF_N 2048
#define M_TOK (S_LEN*BATCH_N)  // 4096
#define QSZ (BATCH_N*H_N*S_LEN*DK_N)  // 2097152 elements per q/k/v plane

typedef __attribute__((ext_vector_type(8))) short short8;
typedef __attribute__((ext_vector_type(4))) float f32x4;
typedef __attribute__((ext_vector_type(16))) float f32x16;
typedef __attribute__((ext_vector_type(4))) unsigned uint4v;

__device__ __forceinline__ unsigned short f2b(float f) {
  union { float f; unsigned u; } v; v.f = f;
  unsigned r = v.u + 0x7FFFu + ((v.u >> 16) & 1u);
  return (unsigned short)(r >> 16);
}
__device__ __forceinline__ float b2f(unsigned short u) {
  union { unsigned u; float f; } v; v.u = ((unsigned)u) << 16; return v.f;
}

// async global->LDS, 16B per lane (dest = wave-uniform base + lane*16).
__device__ __forceinline__ void gl_lds16(const void* g, void* l) {
  __builtin_amdgcn_global_load_lds(
      (__attribute__((address_space(1))) unsigned int*)(unsigned long long)g,
      (__attribute__((address_space(3))) unsigned int*)(unsigned int)(unsigned long long)l,
      16, 0, 0);
}

// ---- f32 -> bf16 cast ----
__global__ void cast_kernel(const float* __restrict__ src,
                            unsigned short* __restrict__ dst, int n) {
  int i = (blockIdx.x * blockDim.x + threadIdx.x) * 4;
  if (i >= n) return;
  float4 v = *(const float4*)(src + i);
  ushort4 o; o.x = f2b(v.x); o.y = f2b(v.y); o.z = f2b(v.z); o.w = f2b(v.w);
  *(ushort4*)(dst + i) = o;
}

// ---- pack key-padding mask into per-tile u64 bitmasks ----
__global__ void maskpack(const int* __restrict__ mm, unsigned long long* __restrict__ bm) {
  int t = threadIdx.x;              // 64 threads: b = t>>5, kt = t&31
  int b = t >> 5, kt = t & 31;
  unsigned long long m = 0ull;
  for (int j = 0; j < 64; j++)
    m |= (unsigned long long)(mm[b*S_LEN + kt*64 + j] != 0) << j;
  bm[b*32 + kt] = m;
}

// ---- LayerNorm: one row of 512 per block (128 threads) -> bf16 out ----
__global__ __launch_bounds__(128) void ln_kernel(const float* __restrict__ in,
                                                 const float* __restrict__ g,
                                                 const float* __restrict__ b,
                                                 unsigned short* __restrict__ out) {
  int row = blockIdx.x, t = threadIdx.x;
  float4 v = ((const float4*)(in + (size_t)row * DM))[t];
  float s  = v.x + v.y + v.z + v.w;
  float ss = v.x*v.x + v.y*v.y + v.z*v.z + v.w*v.w;
  #pragma unroll
  for (int off = 32; off >= 1; off >>= 1) {
    s  += __shfl_xor(s,  off);
    ss += __shfl_xor(ss, off);
  }
  __shared__ float sh[4];
  if ((t & 63) == 0) { sh[(t>>6)*2] = s; sh[(t>>6)*2+1] = ss; }
  __syncthreads();
  s = sh[0] + sh[2]; ss = sh[1] + sh[3];
  float mean = s * (1.f/512.f);
  float inv  = rsqrtf(ss * (1.f/512.f) - mean*mean + 1e-5f);
  float4 gv = ((const float4*)g)[t];
  float4 bv = ((const float4*)b)[t];
  ushort4 o;
  o.x = f2b((v.x-mean)*inv*gv.x + bv.x);
  o.y = f2b((v.y-mean)*inv*gv.y + bv.y);
  o.z = f2b((v.z-mean)*inv*gv.z + bv.z);
  o.w = f2b((v.w-mean)*inv*gv.w + bv.w);
  ((ushort4*)out)[(size_t)row*128 + t] = o;
}

// ---- 64x64-tile GEMM (N=512 cases), double-buffered single-barrier loop ----
template<int RELU, int OUTMODE, int RESID>
__global__ __launch_bounds__(256) void gemm_bt(
    const unsigned short* __restrict__ A, const unsigned short* __restrict__ W,
    const float* __restrict__ bias, const float* __restrict__ resid,
    float* __restrict__ Cf, unsigned short* __restrict__ Cb,
    int M, int N, int K)
{
  __shared__ unsigned short As[2][64*40];
  __shared__ unsigned short Bs[2][64*40];
  int tid = threadIdx.x;
  int lane = tid & 63, w = tid >> 6;
  int wr = w >> 1, wc = w & 1;
  int bm = blockIdx.y * 64, bn = blockIdx.x * 64;
  f32x4 acc[2][2] = {};
  int lrow = tid >> 2;
  int lcg  = (tid & 3) * 8;
  const size_t aoff = (size_t)(bm + lrow) * K + lcg;
  const size_t boff = (size_t)(bn + lrow) * K + lcg;
  int fr = lane & 15, kg = (lane >> 4) * 8;
  // prologue: stage k0=0 into buf0
  short8 pa = *(const short8*)&A[aoff];
  short8 pb = *(const short8*)&W[boff];
  *(short8*)&As[0][lrow*40 + lcg] = pa;
  *(short8*)&Bs[0][lrow*40 + lcg] = pb;
  __syncthreads();
  int cur = 0;
  for (int k0 = 0; k0 < K; k0 += 32) {
    bool hn = (k0 + 32) < K;
    if (hn) {
      pa = *(const short8*)&A[aoff + k0 + 32];
      pb = *(const short8*)&W[boff + k0 + 32];
    }
    short8 af0 = *(const short8*)&As[cur][(wr*32 +      fr)*40 + kg];
    short8 af1 = *(const short8*)&As[cur][(wr*32 + 16 + fr)*40 + kg];
    short8 bf0 = *(const short8*)&Bs[cur][(wc*32 +      fr)*40 + kg];
    short8 bf1 = *(const short8*)&Bs[cur][(wc*32 + 16 + fr)*40 + kg];
    acc[0][0] = __builtin_amdgcn_mfma_f32_16x16x32_bf16(af0, bf0, acc[0][0], 0,0,0);
    acc[0][1] = __builtin_amdgcn_mfma_f32_16x16x32_bf16(af0, bf1, acc[0][1], 0,0,0);
    acc[1][0] = __builtin_amdgcn_mfma_f32_16x16x32_bf16(af1, bf0, acc[1][0], 0,0,0);
    acc[1][1] = __builtin_amdgcn_mfma_f32_16x16x32_bf16(af1, bf1, acc[1][1], 0,0,0);
    if (hn) {
      *(short8*)&As[cur^1][lrow*40 + lcg] = pa;
      *(short8*)&Bs[cur^1][lrow*40 + lcg] = pb;
    }
    __syncthreads();
    cur ^= 1;
  }
  int rbase = (lane >> 4) * 4;
  #pragma unroll
  for (int m = 0; m < 2; m++) {
    #pragma unroll
    for (int n = 0; n < 2; n++) {
      int col = bn + wc*32 + n*16 + (lane & 15);
      float bc = bias[col];
      #pragma unroll
      for (int r = 0; r < 4; r++) {
        int row = bm + wr*32 + m*16 + rbase + r;
        float vv = acc[m][n][r] + bc;
        if (RELU) vv = fmaxf(vv, 0.f);
        if (OUTMODE == 2) {
          int which = col >> 9, hh = (col >> 6) & 7, dd = col & 63;
          size_t idx = ((((size_t)which*BATCH_N + (row & 1))*H_N + hh)*S_LEN + (row >> 1))*DK_N + dd;
          Cb[idx] = f2b(vv);
        } else {
          size_t idx = (size_t)row * N + col;
          if (RESID) vv += resid[idx];
          if (OUTMODE == 1) Cb[idx] = f2b(vv);
          else              Cf[idx] = vv;
        }
      }
    }
  }
}

// ---- 128x128-tile GEMM, global_load_lds staging ----
// OUTMODE 1: bf16 row-major (+RELU). OUTMODE 2: qkv scatter; planes >= VSTART
// are written TRANSPOSED ([b][h][d][s]) so attention consumes V^T directly.
template<int RELU, int OUTMODE, int VSTART>
__global__ __launch_bounds__(256) void gemm128(
    const unsigned short* __restrict__ A, const unsigned short* __restrict__ W,
    const float* __restrict__ bias, unsigned short* __restrict__ Cb,
    int M, int N, int K)
{
  __shared__ unsigned short As[128*32];
  __shared__ unsigned short Bs[128*32];
  int tid = threadIdx.x, lane = tid & 63, w = tid >> 6;
  int bm = blockIdx.y * 128, bn = blockIdx.x * 128;
  int fr = lane & 15, hi = lane >> 4;
  int kg8 = hi*8, rg = hi*4;
  int wm = (w >> 1) * 64, wn = (w & 1) * 64;
  f32x4 acc[4][4] = {};
  const unsigned short* ga0 = A + (size_t)(bm +      (tid>>2))*K + (tid&3)*8;
  const unsigned short* ga1 = A + (size_t)(bm + 64 + (tid>>2))*K + (tid&3)*8;
  const unsigned short* gb0 = W + (size_t)(bn +      (tid>>2))*K + (tid&3)*8;
  const unsigned short* gb1 = W + (size_t)(bn + 64 + (tid>>2))*K + (tid&3)*8;
  unsigned short* lA0 = &As[tid*8];
  unsigned short* lA1 = &As[2048 + tid*8];
  unsigned short* lB0 = &Bs[tid*8];
  unsigned short* lB1 = &Bs[2048 + tid*8];
  for (int k0 = 0; k0 < K; k0 += 32) {
    gl_lds16(ga0 + k0, lA0);
    gl_lds16(ga1 + k0, lA1);
    gl_lds16(gb0 + k0, lB0);
    gl_lds16(gb1 + k0, lB1);
    __syncthreads();
    short8 af[4], bf[4];
    #pragma unroll
    for (int m = 0; m < 4; m++) af[m] = *(const short8*)&As[(wm + m*16 + fr)*32 + kg8];
    #pragma unroll
    for (int n = 0; n < 4; n++) bf[n] = *(const short8*)&Bs[(wn + n*16 + fr)*32 + kg8];
    __builtin_amdgcn_s_setprio(1);
    #pragma unroll
    for (int m = 0; m < 4; m++)
      #pragma unroll
      for (int n = 0; n < 4; n++)
        acc[m][n] = __builtin_amdgcn_mfma_f32_16x16x32_bf16(af[m], bf[n], acc[m][n], 0,0,0);
    __builtin_amdgcn_s_setprio(0);
    __syncthreads();
  }
  #pragma unroll
  for (int m = 0; m < 4; m++) {
    #pragma unroll
    for (int n = 0; n < 4; n++) {
      int col = bn + wn + n*16 + fr;
      float bc = bias[col];
      #pragma unroll
      for (int r = 0; r < 4; r++) {
        int row = bm + wm + m*16 + rg + r;
        float vv = acc[m][n][r] + bc;
        if (RELU) vv = fmaxf(vv, 0.f);
        if (OUTMODE == 2) {
          int which = col >> 9, hh = (col >> 6) & 7, dd = col & 63;
          int srow = row >> 1, bb = row & 1;
          size_t idx;
          if (which >= VSTART)
            idx = (size_t)which*QSZ + (((size_t)bb*H_N + hh)*DK_N + dd)*S_LEN + srow;
          else
            idx = (size_t)which*QSZ + (((size_t)bb*H_N + hh)*S_LEN + srow)*DK_N + dd;
          Cb[idx] = f2b(vv);
        } else {
          Cb[(size_t)row * N + col] = f2b(vv);
        }
      }
    }
  }
}

// ---- 32x32-MFMA flash attention, swapped QK^T, in-register P ----
// Double-buffered K/V staging: single barrier per tile; tile t+1 global loads
// issued before tile t compute (T14), LDS-written after compute, before barrier.
// MODE 0: causal self. MODE 1: key-padding cross (u64 bitmask per tile).
// grid 2048 = (qt 32 x range 4) x 16 pairs; bid = u*16 + p pins pair p to XCD p%8.
template<int MODE>
__global__ __launch_bounds__(256, 4) void attn2(
    const unsigned short* __restrict__ qg, const unsigned short* __restrict__ kpl,
    const unsigned short* __restrict__ vtpl, const unsigned long long* __restrict__ bm,
    unsigned short* __restrict__ opart, float* __restrict__ lpart)
{
  // [buf][Ks | Vt], buf = 0/1; tail = lsum. fb (epilogue) aliases buf0.
  __shared__ unsigned short SM[4*64*72 + 128];
  const int K72 = 64*72;
  float* lsum = (float*)(SM + 4*K72);
  int tid = threadIdx.x;
  int lane = tid & 63, w = tid >> 6;
  int qgp = w & 1, kh2 = w >> 1;
  int l31 = lane & 31, hi5 = lane >> 5;
  int bid = blockIdx.x;
  int p = bid & 15, u = bid >> 4;
  int qt = u >> 2, range = u & 3;
  int h = p & 7, b = p >> 3;
  const size_t sbase = (size_t)(b*H_N + h) * S_LEN;
  int kt0 = range*8, kt1 = kt0 + 7;
  if (MODE == 0) {
    if (kt0 > qt) {   // inactive block: zero partial slice, exit (block-uniform)
      int zr = tid >> 2, zc = (tid & 3) * 16;
      short8 z = {};
      size_t zb = (size_t)range*QSZ + (sbase + (size_t)qt*64 + zr)*DK_N + zc;
      *(short8*)&opart[zb]     = z;
      *(short8*)&opart[zb + 8] = z;
      if (tid < 64) lpart[range*32768 + (int)sbase + qt*64 + tid] = 0.f;
      return;
    }
    if (kt1 > qt) kt1 = qt;
  }
  // Q fragments (B-operand: lane&31 = q-row, elems = d-slice)
  int qrow = qt*64 + qgp*32 + l31;
  short8 qf[4];
  #pragma unroll
  for (int km = 0; km < 4; km++)
    qf[km] = *(const short8*)&qg[(sbase + qrow)*DK_N + km*16 + hi5*8];

  int sr = tid >> 2, sc = (tid & 3) * 16;
  const unsigned short* kbase = &kpl[(sbase + sr)*DK_N + sc];
  const unsigned short* vbase = &vtpl[((size_t)(b*H_N + h)*DK_N + sr)*S_LEN + sc];
  // prologue: stage tile kt0 into buf0
  {
    short8 k0v = *(const short8*)(kbase + (size_t)kt0*64*DK_N);
    short8 k1v = *(const short8*)(kbase + (size_t)kt0*64*DK_N + 8);
    short8 v0v = *(const short8*)(vbase + kt0*64);
    short8 v1v = *(const short8*)(vbase + kt0*64 + 8);
    *(short8*)&SM[sr*72 + sc]            = k0v;
    *(short8*)&SM[sr*72 + sc + 8]        = k1v;
    *(short8*)&SM[K72 + sr*72 + sc]      = v0v;
    *(short8*)&SM[K72 + sr*72 + sc + 8]  = v1v;
  }
  __syncthreads();

  f32x16 oa0 = {}, oa1 = {};
  float lp = 0.f;
  int cur = 0;
  for (int kt = kt0; kt <= kt1; kt++) {
    bool hn = kt < kt1;
    short8 nk0, nk1, nv0, nv1;
    if (hn) {   // issue next-tile loads; waitcnt lands at the LDS write below
      nk0 = *(const short8*)(kbase + (size_t)(kt+1)*64*DK_N);
      nk1 = *(const short8*)(kbase + (size_t)(kt+1)*64*DK_N + 8);
      nv0 = *(const short8*)(vbase + (kt+1)*64);
      nv1 = *(const short8*)(vbase + (kt+1)*64 + 8);
    }
    unsigned short* Ksc = SM + cur*2*K72;
    unsigned short* Vtc = Ksc + K72;
    // ---- S^T = mfma(K, Q): col = q, rows = k ----
    f32x16 sa = {};
    __builtin_amdgcn_s_setprio(1);
    #pragma unroll
    for (int km = 0; km < 4; km++) {
      short8 kf = *(const short8*)&Ksc[(kh2*32 + l31)*72 + km*16 + hi5*8];
      sa = __builtin_amdgcn_mfma_f32_32x32x16_bf16(kf, qf[km], sa, 0, 0, 0);
    }
    __builtin_amdgcn_s_setprio(0);
    // ---- softmax (no max-tracking), mask, in-register ----
    unsigned mlo = 0;
    if (MODE == 1) {
      unsigned long long mw = bm[b*32 + kt];
      mlo = (unsigned)(mw >> (kh2*32 + 4*hi5));
    }
    float pv[16];
    float psum = 0.f;
    int qv = qgp*32 + l31;
    #pragma unroll
    for (int r = 0; r < 16; r++) {
      const int pos = (r & 3) + 8*(r >> 2);
      float e = __expf(sa[r] * 0.125f);
      bool dead;
      if (MODE == 0) dead = (kt == qt) && (kh2*32 + 4*hi5 + pos > qv);
      else           dead = ((mlo >> pos) & 1u) != 0u;
      e = dead ? 0.f : e;
      pv[r] = e;
      psum += e;
    }
    lp += psum;
    // ---- P -> bf16 A-fragments via cvt_pk + permlane32_swap ----
    // swap semantics: vdst.hi <-> vsrc.lo. (vdst=pk[j], vsrc=pk[j+2]):
    //   pk[j]   -> {lo: pk[j]@lo,  hi: pk[j+2]@lo} = fragment word j
    //   pk[j+2] -> {lo: pk[j]@hi,  hi: pk[j+2]@hi} = fragment word j+2
    unsigned pk[8];
    #pragma unroll
    for (int i = 0; i < 8; i++)
      asm("v_cvt_pk_bf16_f32 %0, %1, %2" : "=v"(pk[i]) : "v"(pv[2*i]), "v"(pv[2*i+1]));
    asm("v_permlane32_swap_b32 %0, %1" : "+v"(pk[0]), "+v"(pk[2]));
    asm("v_permlane32_swap_b32 %0, %1" : "+v"(pk[1]), "+v"(pk[3]));
    asm("v_permlane32_swap_b32 %0, %1" : "+v"(pk[4]), "+v"(pk[6]));
    asm("v_permlane32_swap_b32 %0, %1" : "+v"(pk[5]), "+v"(pk[7]));
    uint4v f0v, f1v;
    f0v.x = pk[0]; f0v.y = pk[1]; f0v.z = pk[2]; f0v.w = pk[3];
    f1v.x = pk[4]; f1v.y = pk[5]; f1v.z = pk[6]; f1v.w = pk[7];
    short8 pf0 = *(short8*)&f0v;
    short8 pf1 = *(short8*)&f1v;
    // ---- O += P V: mfma(P, Vt): col = d, rows = q ----
    __builtin_amdgcn_s_setprio(1);
    {
      short8 v00 = *(const short8*)&Vtc[(     l31)*72 + kh2*32 +      hi5*8];
      short8 v01 = *(const short8*)&Vtc[(     l31)*72 + kh2*32 + 16 + hi5*8];
      oa0 = __builtin_amdgcn_mfma_f32_32x32x16_bf16(pf0, v00, oa0, 0, 0, 0);
      oa0 = __builtin_amdgcn_mfma_f32_32x32x16_bf16(pf1, v01, oa0, 0, 0, 0);
      short8 v10 = *(const short8*)&Vtc[(32 + l31)*72 + kh2*32 +      hi5*8];
      short8 v11 = *(const short8*)&Vtc[(32 + l31)*72 + kh2*32 + 16 + hi5*8];
      oa1 = __builtin_amdgcn_mfma_f32_32x32x16_bf16(pf0, v10, oa1, 0, 0, 0);
      oa1 = __builtin_amdgcn_mfma_f32_32x32x16_bf16(pf1, v11, oa1, 0, 0, 0);
    }
    __builtin_amdgcn_s_setprio(0);
    // ---- write next tile into the other buffer (pre-barrier: safe, all waves
    // finished reading buf^1 at the end of iteration t-1) ----
    if (hn) {
      unsigned short* Ksn = SM + (cur^1)*2*K72;
      *(short8*)&Ksn[sr*72 + sc]           = nk0;
      *(short8*)&Ksn[sr*72 + sc + 8]       = nk1;
      *(short8*)&Ksn[K72 + sr*72 + sc]     = nv0;
      *(short8*)&Ksn[K72 + sr*72 + sc + 8] = nv1;
    }
    __syncthreads();
    cur ^= 1;
  }
  // ---- epilogue: combine kh2 halves via LDS, write unnormalized partials ----
  float lptot = lp + __shfl_xor(lp, 32);
  float* fb = (float*)SM;   // 64x64 f32, aliases buffers (all reads done)
  if (kh2 == 1) {
    #pragma unroll
    for (int r = 0; r < 16; r++) {
      const int pos = (r & 3) + 8*(r >> 2);
      int qr = qgp*32 + pos + 4*hi5;
      fb[qr*64 + l31]      = oa0[r];
      fb[qr*64 + 32 + l31] = oa1[r];
    }
    if (lane < 32) lsum[qgp*32 + l31] = lptot;
  }
  __syncthreads();
  if (kh2 == 0) {
    if (lane < 32)
      lpart[range*32768 + (int)sbase + qt*64 + qgp*32 + l31] = lptot + lsum[qgp*32 + l31];
    #pragma unroll
    for (int r = 0; r < 16; r++) {
      const int pos = (r & 3) + 8*(r >> 2);
      int qr = qgp*32 + pos + 4*hi5;
      size_t obase = (size_t)range*QSZ + (sbase + (size_t)qt*64 + qr)*DK_N;
      opart[obase + l31]      = f2b(oa0[r] + fb[qr*64 + l31]);
      opart[obase + 32 + l31] = f2b(oa1[r] + fb[qr*64 + 32 + l31]);
    }
  }
}

// ---- merge the four key-range partials: o = sum(O_r) / sum(l_r) ----
__global__ __launch_bounds__(256) void attn_combine4(
    const unsigned short* __restrict__ op, const float* __restrict__ lp,
    unsigned short* __restrict__ o)
{
  int t = blockIdx.x*256 + threadIdx.x;
  int f = t*8;
  int col = f & 511, row = f >> 9;
  int h = col >> 6, d = col & 63, s = row >> 1, b = row & 1;
  size_t pr = ((size_t)b*H_N + h)*S_LEN + s;
  size_t base = pr*DK_N + d;
  float acc[8] = {0.f,0.f,0.f,0.f,0.f,0.f,0.f,0.f};
  float l = 0.f;
  #pragma unroll
  for (int r = 0; r < 4; r++) {
    short8 a = *(const short8*)&op[(size_t)r*QSZ + base];
    #pragma unroll
    for (int i = 0; i < 8; i++) acc[i] += b2f((unsigned short)a[i]);
    l += lp[r*32768 + (int)pr];
  }
  float inv = 1.f / l;
  short8 r8;
  #pragma unroll
  for (int i = 0; i < 8; i++) r8[i] = (short)f2b(acc[i] * inv);
  *(short8*)&o[(size_t)row*DM + col] = r8;
}

extern "C" void kernel_launch(void* const* d_in, const int* in_sizes, int n_in,
                              void* d_out, int out_size, void* d_ws, size_t ws_size,
                              hipStream_t stream) {
  const float* x       = (const float*)d_in[0];
  const float* memory  = (const float*)d_in[1];
  const int*   memmask = (const int*)d_in[3];
  const float* sa_W = (const float*)d_in[4];
  const float* sa_b = (const float*)d_in[5];
  const float* ca_W = (const float*)d_in[6];
  const float* ca_b = (const float*)d_in[7];
  const float* w1   = (const float*)d_in[8];
  const float* b1   = (const float*)d_in[9];
  const float* w2   = (const float*)d_in[10];
  const float* b2   = (const float*)d_in[11];
  const float* ln_g = (const float*)d_in[12];
  const float* ln_b = (const float*)d_in[13];
  float* out = (float*)d_out;

  char* ws = (char*)d_ws;
  float*          xcur   = (float*)ws;                              // 0..8 MB
  unsigned short* nx_bf  = (unsigned short*)(ws + (8u<<20));        // 8..12 MB
  unsigned short* qkv_sa = (unsigned short*)(ws + (12u<<20));       // 12..24 MB
  unsigned short* q_ca   = (unsigned short*)(ws + (24u<<20));       // 24..28 MB
  unsigned short* kv_ca  = (unsigned short*)(ws + (28u<<20));       // 28..36 MB
  unsigned short* o_bf   = (unsigned short*)(ws + (36u<<20));       // 36..40 MB
  unsigned short* mem_bf = (unsigned short*)(ws + (40u<<20));       // 40..44 MB
  unsigned short* h_bf   = (unsigned short*)(ws + (44u<<20));       // 44..60 MB (FFN)
  unsigned short* opart  = (unsigned short*)(ws + (44u<<20));       // 44..60 MB (attn)
  float*          lpart  = (float*)(ws + (60u<<20));                // 60..60.5 MB
  unsigned long long* bmsk = (unsigned long long*)(ws + (60u<<20) + (1u<<19)); // 512 B
  unsigned short* w_sa   = (unsigned short*)(ws + (61u<<20));       // weights bf16
  unsigned short* w_ca   = w_sa + 4*512*512;
  unsigned short* w_f1   = w_ca + 4*512*512;
  unsigned short* w_f2   = w_f1 + 2048*512;

  cast_kernel<<<1024, 256, 0, stream>>>(sa_W, w_sa, 4*512*512);
  cast_kernel<<<1024, 256, 0, stream>>>(ca_W, w_ca, 4*512*512);
  cast_kernel<<<1024, 256, 0, stream>>>(w1,   w_f1, 2048*512);
  cast_kernel<<<1024, 256, 0, stream>>>(w2,   w_f2, 512*2048);
  cast_kernel<<<2048, 256, 0, stream>>>(memory, mem_bf, M_TOK*512);
  maskpack<<<1, 64, 0, stream>>>(memmask, bmsk);

  dim3 blk(256);
  dim3 g512 (512/64,  4096/64);
  dim3 q128_1536(1536/128, 4096/128);
  dim3 q128_1024(1024/128, 4096/128);
  dim3 q128_2048(2048/128, 4096/128);

  // ---- self-attention block ----
  ln_kernel<<<4096, 128, 0, stream>>>(x, ln_g, ln_b, nx_bf);
  gemm128<0,2,2><<<q128_1536, blk, 0, stream>>>(nx_bf, w_sa, sa_b, qkv_sa, 4096, 1536, 512);
  attn2<0><<<2048, 256, 0, stream>>>(qkv_sa, qkv_sa + QSZ, qkv_sa + 2*QSZ, nullptr, opart, lpart);
  attn_combine4<<<1024, 256, 0, stream>>>(opart, lpart, o_bf);
  gemm_bt<0,0,1><<<g512, blk, 0, stream>>>(o_bf, w_sa + 3*262144, sa_b + 1536, x, xcur, nullptr, 4096, 512, 512);

  // ---- cross-attention block ----
  ln_kernel<<<4096, 128, 0, stream>>>(xcur, ln_g + 512, ln_b + 512, nx_bf);
  gemm_bt<0,2,0><<<g512, blk, 0, stream>>>(nx_bf, w_ca, ca_b, nullptr, nullptr, q_ca, 4096, 512, 512);
  gemm128<0,2,1><<<q128_1024, blk, 0, stream>>>(mem_bf, w_ca + 262144, ca_b + 512, kv_ca, 4096, 1024, 512);
  attn2<1><<<2048, 256, 0, stream>>>(q_ca, kv_ca, kv_ca + QSZ, bmsk, opart, lpart);
  attn_combine4<<<1024, 256, 0, stream>>>(opart, lpart, o_bf);
  gemm_bt<0,0,1><<<g512, blk, 0, stream>>>(o_bf, w_ca + 3*262144, ca_b + 1536, xcur, xcur, nullptr, 4096, 512, 512);

  // ---- FFN block ----
  ln_kernel<<<4096, 128, 0, stream>>>(xcur, ln_g + 1024, ln_b + 1024, nx_bf);
  gemm128<1,1,0><<<q128_2048, blk, 0, stream>>>(nx_bf, w_f1, b1, h_bf, 4096, 2048, 512);
  gemm_bt<0,0,1><<<g512, blk, 0, stream>>>(h_bf, w_f2, b2, xcur, out, nullptr, 4096, 512, 2048);
}

// Round 9
// 208.687 us; speedup vs baseline: 1.0455x; 1.0455x over previous
//
#include <hip/hip_runtime.h>

#define S_LEN 2048
#define BATCH_N 2
#define DM 512
#define H_N 8
#define DK_N 64
#define FF_N 2048
#define M_TOK (S_LEN*BATCH_N)  // 4096
#define QSZ (BATCH_N*H_N*S_LEN*DK_N)  // 2097152 elements per q/k/v plane

typedef __attribute__((ext_vector_type(8))) short short8;
typedef __attribute__((ext_vector_type(4))) float f32x4;
typedef __attribute__((ext_vector_type(16))) float f32x16;
typedef __attribute__((ext_vector_type(4))) unsigned uint4v;

__device__ __forceinline__ unsigned short f2b(float f) {
  union { float f; unsigned u; } v; v.f = f;
  unsigned r = v.u + 0x7FFFu + ((v.u >> 16) & 1u);
  return (unsigned short)(r >> 16);
}
__device__ __forceinline__ float b2f(unsigned short u) {
  union { unsigned u; float f; } v; v.u = ((unsigned)u) << 16; return v.f;
}

// async global->LDS, 16B per lane (dest = wave-uniform base + lane*16).
__device__ __forceinline__ void gl_lds16(const void* g, void* l) {
  __builtin_amdgcn_global_load_lds(
      (__attribute__((address_space(1))) unsigned int*)(unsigned long long)g,
      (__attribute__((address_space(3))) unsigned int*)(unsigned int)(unsigned long long)l,
      16, 0, 0);
}

__device__ __forceinline__ void cast4(const float* __restrict__ src,
                                      unsigned short* __restrict__ dst, int i) {
  float4 v = *(const float4*)(src + i);
  ushort4 o; o.x = f2b(v.x); o.y = f2b(v.y); o.z = f2b(v.z); o.w = f2b(v.w);
  *(ushort4*)(dst + i) = o;
}

// ---- fused prep: all weight/memory casts + mask packing, one launch ----
__global__ __launch_bounds__(256) void prep_kernel(
    const float* __restrict__ sa_W, const float* __restrict__ ca_W,
    const float* __restrict__ w1, const float* __restrict__ w2,
    const float* __restrict__ memory, const int* __restrict__ mm,
    unsigned short* __restrict__ o_sa, unsigned short* __restrict__ o_ca,
    unsigned short* __restrict__ o_w1, unsigned short* __restrict__ o_w2,
    unsigned short* __restrict__ o_mem, unsigned long long* __restrict__ bmo)
{
  int blk = blockIdx.x, t = threadIdx.x;
  if (blk < 1024)      cast4(sa_W, o_sa, (blk*256 + t)*4);
  else if (blk < 2048) cast4(ca_W, o_ca, ((blk-1024)*256 + t)*4);
  else if (blk < 3072) cast4(w1,   o_w1, ((blk-2048)*256 + t)*4);
  else if (blk < 4096) cast4(w2,   o_w2, ((blk-3072)*256 + t)*4);
  else if (blk < 6144) cast4(memory, o_mem, ((blk-4096)*256 + t)*4);
  else if (t < 64) {
    int b = t >> 5, kt = t & 31;
    unsigned long long m = 0ull;
    for (int j = 0; j < 64; j++)
      m |= (unsigned long long)(mm[b*S_LEN + kt*64 + j] != 0) << j;
    bmo[b*32 + kt] = m;
  }
}

// ---- LayerNorm: one row of 512 per block (128 threads) -> bf16 out ----
__global__ __launch_bounds__(128) void ln_kernel(const float* __restrict__ in,
                                                 const float* __restrict__ g,
                                                 const float* __restrict__ b,
                                                 unsigned short* __restrict__ out) {
  int row = blockIdx.x, t = threadIdx.x;
  float4 v = ((const float4*)(in + (size_t)row * DM))[t];
  float s  = v.x + v.y + v.z + v.w;
  float ss = v.x*v.x + v.y*v.y + v.z*v.z + v.w*v.w;
  #pragma unroll
  for (int off = 32; off >= 1; off >>= 1) {
    s  += __shfl_xor(s,  off);
    ss += __shfl_xor(ss, off);
  }
  __shared__ float sh[4];
  if ((t & 63) == 0) { sh[(t>>6)*2] = s; sh[(t>>6)*2+1] = ss; }
  __syncthreads();
  s = sh[0] + sh[2]; ss = sh[1] + sh[3];
  float mean = s * (1.f/512.f);
  float inv  = rsqrtf(ss * (1.f/512.f) - mean*mean + 1e-5f);
  float4 gv = ((const float4*)g)[t];
  float4 bv = ((const float4*)b)[t];
  ushort4 o;
  o.x = f2b((v.x-mean)*inv*gv.x + bv.x);
  o.y = f2b((v.y-mean)*inv*gv.y + bv.y);
  o.z = f2b((v.z-mean)*inv*gv.z + bv.z);
  o.w = f2b((v.w-mean)*inv*gv.w + bv.w);
  ((ushort4*)out)[(size_t)row*128 + t] = o;
}

// ---- 64x64-tile GEMM (N=512 cases), double-buffered single-barrier loop ----
template<int RELU, int OUTMODE, int RESID>
__global__ __launch_bounds__(256) void gemm_bt(
    const unsigned short* __restrict__ A, const unsigned short* __restrict__ W,
    const float* __restrict__ bias, const float* __restrict__ resid,
    float* __restrict__ Cf, unsigned short* __restrict__ Cb,
    int M, int N, int K)
{
  __shared__ unsigned short As[2][64*40];
  __shared__ unsigned short Bs[2][64*40];
  int tid = threadIdx.x;
  int lane = tid & 63, w = tid >> 6;
  int wr = w >> 1, wc = w & 1;
  int bm = blockIdx.y * 64, bn = blockIdx.x * 64;
  f32x4 acc[2][2] = {};
  int lrow = tid >> 2;
  int lcg  = (tid & 3) * 8;
  const size_t aoff = (size_t)(bm + lrow) * K + lcg;
  const size_t boff = (size_t)(bn + lrow) * K + lcg;
  int fr = lane & 15, kg = (lane >> 4) * 8;
  short8 pa = *(const short8*)&A[aoff];
  short8 pb = *(const short8*)&W[boff];
  *(short8*)&As[0][lrow*40 + lcg] = pa;
  *(short8*)&Bs[0][lrow*40 + lcg] = pb;
  __syncthreads();
  int cur = 0;
  for (int k0 = 0; k0 < K; k0 += 32) {
    bool hn = (k0 + 32) < K;
    if (hn) {
      pa = *(const short8*)&A[aoff + k0 + 32];
      pb = *(const short8*)&W[boff + k0 + 32];
    }
    short8 af0 = *(const short8*)&As[cur][(wr*32 +      fr)*40 + kg];
    short8 af1 = *(const short8*)&As[cur][(wr*32 + 16 + fr)*40 + kg];
    short8 bf0 = *(const short8*)&Bs[cur][(wc*32 +      fr)*40 + kg];
    short8 bf1 = *(const short8*)&Bs[cur][(wc*32 + 16 + fr)*40 + kg];
    acc[0][0] = __builtin_amdgcn_mfma_f32_16x16x32_bf16(af0, bf0, acc[0][0], 0,0,0);
    acc[0][1] = __builtin_amdgcn_mfma_f32_16x16x32_bf16(af0, bf1, acc[0][1], 0,0,0);
    acc[1][0] = __builtin_amdgcn_mfma_f32_16x16x32_bf16(af1, bf0, acc[1][0], 0,0,0);
    acc[1][1] = __builtin_amdgcn_mfma_f32_16x16x32_bf16(af1, bf1, acc[1][1], 0,0,0);
    if (hn) {
      *(short8*)&As[cur^1][lrow*40 + lcg] = pa;
      *(short8*)&Bs[cur^1][lrow*40 + lcg] = pb;
    }
    __syncthreads();
    cur ^= 1;
  }
  int rbase = (lane >> 4) * 4;
  #pragma unroll
  for (int m = 0; m < 2; m++) {
    #pragma unroll
    for (int n = 0; n < 2; n++) {
      int col = bn + wc*32 + n*16 + (lane & 15);
      float bc = bias[col];
      #pragma unroll
      for (int r = 0; r < 4; r++) {
        int row = bm + wr*32 + m*16 + rbase + r;
        float vv = acc[m][n][r] + bc;
        if (RELU) vv = fmaxf(vv, 0.f);
        if (OUTMODE == 2) {
          int which = col >> 9, hh = (col >> 6) & 7, dd = col & 63;
          size_t idx = ((((size_t)which*BATCH_N + (row & 1))*H_N + hh)*S_LEN + (row >> 1))*DK_N + dd;
          Cb[idx] = f2b(vv);
        } else {
          size_t idx = (size_t)row * N + col;
          if (RESID) vv += resid[idx];
          if (OUTMODE == 1) Cb[idx] = f2b(vv);
          else              Cf[idx] = vv;
        }
      }
    }
  }
}

// ---- 128x128-tile GEMM, global_load_lds staging ----
// OUTMODE 1: bf16 row-major (+RELU). OUTMODE 2: qkv scatter; planes >= VSTART
// are written TRANSPOSED ([b][h][d][s]) so attention consumes V^T directly.
template<int RELU, int OUTMODE, int VSTART>
__global__ __launch_bounds__(256) void gemm128(
    const unsigned short* __restrict__ A, const unsigned short* __restrict__ W,
    const float* __restrict__ bias, unsigned short* __restrict__ Cb,
    int M, int N, int K)
{
  __shared__ unsigned short As[128*32];
  __shared__ unsigned short Bs[128*32];
  int tid = threadIdx.x, lane = tid & 63, w = tid >> 6;
  int bm = blockIdx.y * 128, bn = blockIdx.x * 128;
  int fr = lane & 15, hi = lane >> 4;
  int kg8 = hi*8, rg = hi*4;
  int wm = (w >> 1) * 64, wn = (w & 1) * 64;
  f32x4 acc[4][4] = {};
  const unsigned short* ga0 = A + (size_t)(bm +      (tid>>2))*K + (tid&3)*8;
  const unsigned short* ga1 = A + (size_t)(bm + 64 + (tid>>2))*K + (tid&3)*8;
  const unsigned short* gb0 = W + (size_t)(bn +      (tid>>2))*K + (tid&3)*8;
  const unsigned short* gb1 = W + (size_t)(bn + 64 + (tid>>2))*K + (tid&3)*8;
  unsigned short* lA0 = &As[tid*8];
  unsigned short* lA1 = &As[2048 + tid*8];
  unsigned short* lB0 = &Bs[tid*8];
  unsigned short* lB1 = &Bs[2048 + tid*8];
  for (int k0 = 0; k0 < K; k0 += 32) {
    gl_lds16(ga0 + k0, lA0);
    gl_lds16(ga1 + k0, lA1);
    gl_lds16(gb0 + k0, lB0);
    gl_lds16(gb1 + k0, lB1);
    __syncthreads();
    short8 af[4], bf[4];
    #pragma unroll
    for (int m = 0; m < 4; m++) af[m] = *(const short8*)&As[(wm + m*16 + fr)*32 + kg8];
    #pragma unroll
    for (int n = 0; n < 4; n++) bf[n] = *(const short8*)&Bs[(wn + n*16 + fr)*32 + kg8];
    __builtin_amdgcn_s_setprio(1);
    #pragma unroll
    for (int m = 0; m < 4; m++)
      #pragma unroll
      for (int n = 0; n < 4; n++)
        acc[m][n] = __builtin_amdgcn_mfma_f32_16x16x32_bf16(af[m], bf[n], acc[m][n], 0,0,0);
    __builtin_amdgcn_s_setprio(0);
    __syncthreads();
  }
  #pragma unroll
  for (int m = 0; m < 4; m++) {
    #pragma unroll
    for (int n = 0; n < 4; n++) {
      int col = bn + wn + n*16 + fr;
      float bc = bias[col];
      #pragma unroll
      for (int r = 0; r < 4; r++) {
        int row = bm + wm + m*16 + rg + r;
        float vv = acc[m][n][r] + bc;
        if (RELU) vv = fmaxf(vv, 0.f);
        if (OUTMODE == 2) {
          int which = col >> 9, hh = (col >> 6) & 7, dd = col & 63;
          int srow = row >> 1, bb = row & 1;
          size_t idx;
          if (which >= VSTART)
            idx = (size_t)which*QSZ + (((size_t)bb*H_N + hh)*DK_N + dd)*S_LEN + srow;
          else
            idx = (size_t)which*QSZ + (((size_t)bb*H_N + hh)*S_LEN + srow)*DK_N + dd;
          Cb[idx] = f2b(vv);
        } else {
          Cb[(size_t)row * N + col] = f2b(vv);
        }
      }
    }
  }
}

// ---- 32x32-MFMA flash attention v3: 128 q-rows/block, wave owns full rows ----
// MODE 0: causal self. MODE 1: key-padding cross (u64 bitmask per tile).
// grid 1024 = (qtile 16 x range 4) x 16 pairs; bid = u*16 + p pins pair p to XCD p%8.
// Block: 256 thr = 4 waves; wave w owns q-rows [qtile*128 + w*32, +32), ALL keys
// of each 64-key tile (two 32-key halves sequentially). No cross-wave O combine.
// No-max softmax -> additive partials per 512-key range; attn_combine4 merges.
// K staged [k][d] stride 72; V from GEMM-transposed plane -> Vt[d][k] stride 72.
// P in registers via swapped QK^T (col=q) + cvt_pk_bf16 + permlane32_swap.
template<int MODE>
__global__ __launch_bounds__(256, 3) void attn3(
    const unsigned short* __restrict__ qg, const unsigned short* __restrict__ kpl,
    const unsigned short* __restrict__ vtpl, const unsigned long long* __restrict__ bm,
    unsigned short* __restrict__ opart, float* __restrict__ lpart)
{
  __shared__ unsigned short SM[2*64*72];   // Ks | Vt
  unsigned short* Ks = SM;
  unsigned short* Vt = SM + 64*72;
  int tid = threadIdx.x;
  int lane = tid & 63, w = tid >> 6;
  int l31 = lane & 31, hi5 = lane >> 5;
  int bid = blockIdx.x;
  int p = bid & 15, u = bid >> 4;
  int qtile = u >> 2, range = u & 3;
  int h = p & 7, b = p >> 3;
  const size_t sbase = (size_t)(b*H_N + h) * S_LEN;
  int kt0 = range*8, kt1 = kt0 + 7;
  if (MODE == 0) {
    int ktmax_tile = qtile*2 + 1;     // last key-tile touching rows of this q-tile
    if (kt0 > ktmax_tile) {           // inactive: zero partial slice, exit
      int zr = tid >> 1, zc = (tid & 1) * 32;
      short8 z = {};
      size_t zb = (size_t)range*QSZ + (sbase + (size_t)qtile*128 + zr)*DK_N + zc;
      *(short8*)&opart[zb]      = z;
      *(short8*)&opart[zb + 8]  = z;
      *(short8*)&opart[zb + 16] = z;
      *(short8*)&opart[zb + 24] = z;
      if (tid < 128) lpart[range*32768 + (int)sbase + qtile*128 + tid] = 0.f;
      return;
    }
    if (kt1 > ktmax_tile) kt1 = ktmax_tile;
  }
  int qrow = qtile*128 + w*32 + l31;  // this lane's q-row (global s index)
  short8 qf[4];
  #pragma unroll
  for (int km = 0; km < 4; km++)
    qf[km] = *(const short8*)&qg[(sbase + qrow)*DK_N + km*16 + hi5*8];

  int sr = tid >> 2, sc = (tid & 3) * 16;
  const unsigned short* kbase = &kpl[(sbase + sr)*DK_N + sc];
  const unsigned short* vbase = &vtpl[((size_t)(b*H_N + h)*DK_N + sr)*S_LEN + sc];

  f32x16 oa0 = {}, oa1 = {};
  float lp = 0.f;
  for (int kt = kt0; kt <= kt1; kt++) {
    __syncthreads();   // prev-tile readers done
    {
      const unsigned short* kg = kbase + (size_t)kt*64*DK_N;
      const unsigned short* vg = vbase + kt*64;
      *(short8*)&Ks[sr*72 + sc]     = *(const short8*)kg;
      *(short8*)&Ks[sr*72 + sc + 8] = *(const short8*)(kg + 8);
      *(short8*)&Vt[sr*72 + sc]     = *(const short8*)vg;
      *(short8*)&Vt[sr*72 + sc + 8] = *(const short8*)(vg + 8);
    }
    __syncthreads();
    #pragma unroll
    for (int kb = 0; kb < 2; kb++) {
      // ---- S^T = mfma(K, Q): col = q (lane), rows = k ----
      f32x16 sa = {};
      __builtin_amdgcn_s_setprio(1);
      #pragma unroll
      for (int km = 0; km < 4; km++) {
        short8 kf = *(const short8*)&Ks[(kb*32 + l31)*72 + km*16 + hi5*8];
        sa = __builtin_amdgcn_mfma_f32_32x32x16_bf16(kf, qf[km], sa, 0, 0, 0);
      }
      __builtin_amdgcn_s_setprio(0);
      // ---- softmax (no max-tracking), mask ----
      unsigned mlo = 0;
      if (MODE == 1) mlo = (unsigned)(bm[b*32 + kt] >> (kb*32 + 4*hi5));
      float pv[16];
      float psum = 0.f;
      #pragma unroll
      for (int r = 0; r < 16; r++) {
        const int pos = (r & 3) + 8*(r >> 2);
        float e = __expf(sa[r] * 0.125f);
        bool dead;
        if (MODE == 0) dead = (kt*64 + kb*32 + 4*hi5 + pos) > qrow;
        else           dead = ((mlo >> pos) & 1u) != 0u;
        e = dead ? 0.f : e;
        pv[r] = e;
        psum += e;
      }
      lp += psum;
      // ---- P -> bf16 A-fragments (vdst.hi <-> vsrc.lo swap) ----
      unsigned pk[8];
      #pragma unroll
      for (int i = 0; i < 8; i++)
        asm("v_cvt_pk_bf16_f32 %0, %1, %2" : "=v"(pk[i]) : "v"(pv[2*i]), "v"(pv[2*i+1]));
      asm("v_permlane32_swap_b32 %0, %1" : "+v"(pk[0]), "+v"(pk[2]));
      asm("v_permlane32_swap_b32 %0, %1" : "+v"(pk[1]), "+v"(pk[3]));
      asm("v_permlane32_swap_b32 %0, %1" : "+v"(pk[4]), "+v"(pk[6]));
      asm("v_permlane32_swap_b32 %0, %1" : "+v"(pk[5]), "+v"(pk[7]));
      uint4v f0v, f1v;
      f0v.x = pk[0]; f0v.y = pk[1]; f0v.z = pk[2]; f0v.w = pk[3];
      f1v.x = pk[4]; f1v.y = pk[5]; f1v.z = pk[6]; f1v.w = pk[7];
      short8 pf0 = *(short8*)&f0v;
      short8 pf1 = *(short8*)&f1v;
      // ---- O += P V ----
      __builtin_amdgcn_s_setprio(1);
      {
        short8 v00 = *(const short8*)&Vt[(     l31)*72 + kb*32 +      hi5*8];
        short8 v01 = *(const short8*)&Vt[(     l31)*72 + kb*32 + 16 + hi5*8];
        oa0 = __builtin_amdgcn_mfma_f32_32x32x16_bf16(pf0, v00, oa0, 0, 0, 0);
        oa0 = __builtin_amdgcn_mfma_f32_32x32x16_bf16(pf1, v01, oa0, 0, 0, 0);
        short8 v10 = *(const short8*)&Vt[(32 + l31)*72 + kb*32 +      hi5*8];
        short8 v11 = *(const short8*)&Vt[(32 + l31)*72 + kb*32 + 16 + hi5*8];
        oa1 = __builtin_amdgcn_mfma_f32_32x32x16_bf16(pf0, v10, oa1, 0, 0, 0);
        oa1 = __builtin_amdgcn_mfma_f32_32x32x16_bf16(pf1, v11, oa1, 0, 0, 0);
      }
      __builtin_amdgcn_s_setprio(0);
    }
  }
  // ---- epilogue: per-wave complete rows -> direct partial writes ----
  float lptot = lp + __shfl_xor(lp, 32);   // combine the two hi5 key-subsets
  if (lane < 32)
    lpart[range*32768 + (int)sbase + qtile*128 + w*32 + l31] = lptot;
  #pragma unroll
  for (int r = 0; r < 16; r++) {
    const int pos = (r & 3) + 8*(r >> 2);
    int qr = qtile*128 + w*32 + pos + 4*hi5;
    size_t obase = (size_t)range*QSZ + (sbase + (size_t)qr)*DK_N;
    opart[obase + l31]      = f2b(oa0[r]);
    opart[obase + 32 + l31] = f2b(oa1[r]);
  }
}

// ---- merge the four key-range partials: o = sum(O_r) / sum(l_r) ----
__global__ __launch_bounds__(256) void attn_combine4(
    const unsigned short* __restrict__ op, const float* __restrict__ lp,
    unsigned short* __restrict__ o)
{
  int t = blockIdx.x*256 + threadIdx.x;
  int f = t*8;
  int col = f & 511, row = f >> 9;
  int h = col >> 6, d = col & 63, s = row >> 1, b = row & 1;
  size_t pr = ((size_t)b*H_N + h)*S_LEN + s;
  size_t base = pr*DK_N + d;
  float acc[8] = {0.f,0.f,0.f,0.f,0.f,0.f,0.f,0.f};
  float l = 0.f;
  #pragma unroll
  for (int r = 0; r < 4; r++) {
    short8 a = *(const short8*)&op[(size_t)r*QSZ + base];
    #pragma unroll
    for (int i = 0; i < 8; i++) acc[i] += b2f((unsigned short)a[i]);
    l += lp[r*32768 + (int)pr];
  }
  float inv = 1.f / l;
  short8 r8;
  #pragma unroll
  for (int i = 0; i < 8; i++) r8[i] = (short)f2b(acc[i] * inv);
  *(short8*)&o[(size_t)row*DM + col] = r8;
}

extern "C" void kernel_launch(void* const* d_in, const int* in_sizes, int n_in,
                              void* d_out, int out_size, void* d_ws, size_t ws_size,
                              hipStream_t stream) {
  const float* x       = (const float*)d_in[0];
  const float* memory  = (const float*)d_in[1];
  const int*   memmask = (const int*)d_in[3];
  const float* sa_W = (const float*)d_in[4];
  const float* sa_b = (const float*)d_in[5];
  const float* ca_W = (const float*)d_in[6];
  const float* ca_b = (const float*)d_in[7];
  const float* w1   = (const float*)d_in[8];
  const float* b1   = (const float*)d_in[9];
  const float* w2   = (const float*)d_in[10];
  const float* b2   = (const float*)d_in[11];
  const float* ln_g = (const float*)d_in[12];
  const float* ln_b = (const float*)d_in[13];
  float* out = (float*)d_out;

  char* ws = (char*)d_ws;
  float*          xcur   = (float*)ws;                              // 0..8 MB
  unsigned short* nx_bf  = (unsigned short*)(ws + (8u<<20));        // 8..12 MB
  unsigned short* qkv_sa = (unsigned short*)(ws + (12u<<20));       // 12..24 MB
  unsigned short* q_ca   = (unsigned short*)(ws + (24u<<20));       // 24..28 MB
  unsigned short* kv_ca  = (unsigned short*)(ws + (28u<<20));       // 28..36 MB
  unsigned short* o_bf   = (unsigned short*)(ws + (36u<<20));       // 36..40 MB
  unsigned short* mem_bf = (unsigned short*)(ws + (40u<<20));       // 40..44 MB
  unsigned short* h_bf   = (unsigned short*)(ws + (44u<<20));       // 44..60 MB (FFN)
  unsigned short* opart  = (unsigned short*)(ws + (44u<<20));       // 44..60 MB (attn)
  float*          lpart  = (float*)(ws + (60u<<20));                // 60..60.5 MB
  unsigned long long* bmsk = (unsigned long long*)(ws + (60u<<20) + (1u<<19)); // 512 B
  unsigned short* w_sa   = (unsigned short*)(ws + (61u<<20));       // weights bf16
  unsigned short* w_ca   = w_sa + 4*512*512;
  unsigned short* w_f1   = w_ca + 4*512*512;
  unsigned short* w_f2   = w_f1 + 2048*512;

  prep_kernel<<<6145, 256, 0, stream>>>(sa_W, ca_W, w1, w2, memory, memmask,
                                        w_sa, w_ca, w_f1, w_f2, mem_bf, bmsk);

  dim3 blk(256);
  dim3 g512 (512/64,  4096/64);
  dim3 q128_1536(1536/128, 4096/128);
  dim3 q128_1024(1024/128, 4096/128);
  dim3 q128_2048(2048/128, 4096/128);

  // ---- self-attention block ----
  ln_kernel<<<4096, 128, 0, stream>>>(x, ln_g, ln_b, nx_bf);
  gemm128<0,2,2><<<q128_1536, blk, 0, stream>>>(nx_bf, w_sa, sa_b, qkv_sa, 4096, 1536, 512);
  attn3<0><<<1024, 256, 0, stream>>>(qkv_sa, qkv_sa + QSZ, qkv_sa + 2*QSZ, nullptr, opart, lpart);
  attn_combine4<<<1024, 256, 0, stream>>>(opart, lpart, o_bf);
  gemm_bt<0,0,1><<<g512, blk, 0, stream>>>(o_bf, w_sa + 3*262144, sa_b + 1536, x, xcur, nullptr, 4096, 512, 512);

  // ---- cross-attention block ----
  ln_kernel<<<4096, 128, 0, stream>>>(xcur, ln_g + 512, ln_b + 512, nx_bf);
  gemm_bt<0,2,0><<<g512, blk, 0, stream>>>(nx_bf, w_ca, ca_b, nullptr, nullptr, q_ca, 4096, 512, 512);
  gemm128<0,2,1><<<q128_1024, blk, 0, stream>>>(mem_bf, w_ca + 262144, ca_b + 512, kv_ca, 4096, 1024, 512);
  attn3<1><<<1024, 256, 0, stream>>>(q_ca, kv_ca, kv_ca + QSZ, bmsk, opart, lpart);
  attn_combine4<<<1024, 256, 0, stream>>>(opart, lpart, o_bf);
  gemm_bt<0,0,1><<<g512, blk, 0, stream>>>(o_bf, w_ca + 3*262144, ca_b + 1536, xcur, xcur, nullptr, 4096, 512, 512);

  // ---- FFN block ----
  ln_kernel<<<4096, 128, 0, stream>>>(xcur, ln_g + 1024, ln_b + 1024, nx_bf);
  gemm128<1,1,0><<<q128_2048, blk, 0, stream>>>(nx_bf, w_f1, b1, h_bf, 4096, 2048, 512);
  gemm_bt<0,0,1><<<g512, blk, 0, stream>>>(h_bf, w_f2, b2, xcur, out, nullptr, 4096, 512, 2048);
}

// Round 10
// 201.576 us; speedup vs baseline: 1.0824x; 1.0353x over previous
//
#include <hip/hip_runtime.h>

#define S_LEN 2048
#define BATCH_N 2
#define DM 512
#define H_N 8
#define DK_N 64
#define FF_N 2048
#define M_TOK (S_LEN*BATCH_N)  // 4096
#define QSZ (BATCH_N*H_N*S_LEN*DK_N)  // 2097152 elements per q/k/v plane
#define MN_PART 2097152          // 4096*512 f32 elems per FFN2 partial

typedef __attribute__((ext_vector_type(8))) short short8;
typedef __attribute__((ext_vector_type(4))) float f32x4;
typedef __attribute__((ext_vector_type(16))) float f32x16;
typedef __attribute__((ext_vector_type(4))) unsigned uint4v;

__device__ __forceinline__ unsigned short f2b(float f) {
  union { float f; unsigned u; } v; v.f = f;
  unsigned r = v.u + 0x7FFFu + ((v.u >> 16) & 1u);
  return (unsigned short)(r >> 16);
}
__device__ __forceinline__ float b2f(unsigned short u) {
  union { unsigned u; float f; } v; v.u = ((unsigned)u) << 16; return v.f;
}

// async global->LDS, 16B per lane (dest = wave-uniform base + lane*16).
__device__ __forceinline__ void gl_lds16(const void* g, void* l) {
  __builtin_amdgcn_global_load_lds(
      (__attribute__((address_space(1))) unsigned int*)(unsigned long long)g,
      (__attribute__((address_space(3))) unsigned int*)(unsigned int)(unsigned long long)l,
      16, 0, 0);
}

__device__ __forceinline__ void cast4(const float* __restrict__ src,
                                      unsigned short* __restrict__ dst, int i) {
  float4 v = *(const float4*)(src + i);
  ushort4 o; o.x = f2b(v.x); o.y = f2b(v.y); o.z = f2b(v.z); o.w = f2b(v.w);
  *(ushort4*)(dst + i) = o;
}

// ---- wave-per-row LayerNorm (512 cols, 8 f32/lane, shfl-only) ----
__device__ __forceinline__ void ln_row_wave(const float* __restrict__ in,
    const float* __restrict__ g, const float* __restrict__ b,
    unsigned short* __restrict__ out, int row, int lane) {
  const float4* src = (const float4*)(in + (size_t)row * DM);
  float4 v0 = src[lane*2], v1 = src[lane*2 + 1];
  float s  = v0.x+v0.y+v0.z+v0.w + v1.x+v1.y+v1.z+v1.w;
  float ss = v0.x*v0.x+v0.y*v0.y+v0.z*v0.z+v0.w*v0.w
           + v1.x*v1.x+v1.y*v1.y+v1.z*v1.z+v1.w*v1.w;
  #pragma unroll
  for (int off = 32; off >= 1; off >>= 1) {
    s  += __shfl_xor(s,  off);
    ss += __shfl_xor(ss, off);
  }
  float mean = s * (1.f/512.f);
  float inv  = rsqrtf(ss * (1.f/512.f) - mean*mean + 1e-5f);
  float4 g0 = ((const float4*)g)[lane*2], g1 = ((const float4*)g)[lane*2 + 1];
  float4 b0 = ((const float4*)b)[lane*2], b1 = ((const float4*)b)[lane*2 + 1];
  ushort4 o0, o1;
  o0.x = f2b((v0.x-mean)*inv*g0.x + b0.x);
  o0.y = f2b((v0.y-mean)*inv*g0.y + b0.y);
  o0.z = f2b((v0.z-mean)*inv*g0.z + b0.z);
  o0.w = f2b((v0.w-mean)*inv*g0.w + b0.w);
  o1.x = f2b((v1.x-mean)*inv*g1.x + b1.x);
  o1.y = f2b((v1.y-mean)*inv*g1.y + b1.y);
  o1.z = f2b((v1.z-mean)*inv*g1.z + b1.z);
  o1.w = f2b((v1.w-mean)*inv*g1.w + b1.w);
  ushort4* dst = (ushort4*)(out + (size_t)row * DM);
  dst[lane*2]     = o0;
  dst[lane*2 + 1] = o1;
}

// ---- fused prep: weight/memory casts + mask pack + LN1 ----
__global__ __launch_bounds__(256) void prep_kernel(
    const float* __restrict__ sa_W, const float* __restrict__ ca_W,
    const float* __restrict__ w1, const float* __restrict__ w2,
    const float* __restrict__ memory, const int* __restrict__ mm,
    const float* __restrict__ x, const float* __restrict__ ln_g,
    const float* __restrict__ ln_b,
    unsigned short* __restrict__ o_sa, unsigned short* __restrict__ o_ca,
    unsigned short* __restrict__ o_w1, unsigned short* __restrict__ o_w2,
    unsigned short* __restrict__ o_mem, unsigned long long* __restrict__ bmo,
    unsigned short* __restrict__ nx)
{
  int blk = blockIdx.x, t = threadIdx.x;
  if (blk < 1024)      cast4(sa_W, o_sa, (blk*256 + t)*4);
  else if (blk < 2048) cast4(ca_W, o_ca, ((blk-1024)*256 + t)*4);
  else if (blk < 3072) cast4(w1,   o_w1, ((blk-2048)*256 + t)*4);
  else if (blk < 4096) cast4(w2,   o_w2, ((blk-3072)*256 + t)*4);
  else if (blk < 6144) cast4(memory, o_mem, ((blk-4096)*256 + t)*4);
  else if (blk == 6144) {
    if (t < 64) {
      int b = t >> 5, kt = t & 31;
      unsigned long long m = 0ull;
      for (int j = 0; j < 64; j++)
        m |= (unsigned long long)(mm[b*S_LEN + kt*64 + j] != 0) << j;
      bmo[b*32 + kt] = m;
    }
  } else {
    int row = (blk - 6145)*4 + (t >> 6);
    ln_row_wave(x, ln_g, ln_b, nx, row, t & 63);
  }
}

// ---- standalone LN (4 rows / 256-thr block) ----
__global__ __launch_bounds__(256) void ln4_kernel(const float* __restrict__ in,
                                                  const float* __restrict__ g,
                                                  const float* __restrict__ b,
                                                  unsigned short* __restrict__ out) {
  ln_row_wave(in, g, b, out, blockIdx.x*4 + (threadIdx.x >> 6), threadIdx.x & 63);
}

// ---- 64x64-tile GEMM, dbuf single-barrier. Kstride = A/W row stride;
// K = this launch's K-chunk length; blockIdx.z = K-chunk (split-K, OUTMODE 3).
// OUTMODE 0: f32 +resid, 1: bf16, 2: bf16 qkv scatter, 3: f32 partial (no bias).
template<int RELU, int OUTMODE, int RESID>
__global__ __launch_bounds__(256) void gemm_bt(
    const unsigned short* __restrict__ A, const unsigned short* __restrict__ W,
    const float* __restrict__ bias, const float* __restrict__ resid,
    float* __restrict__ Cf, unsigned short* __restrict__ Cb,
    int M, int N, int K, int Kstride)
{
  __shared__ unsigned short As[2][64*40];
  __shared__ unsigned short Bs[2][64*40];
  int tid = threadIdx.x;
  int lane = tid & 63, w = tid >> 6;
  int wr = w >> 1, wc = w & 1;
  int bm = blockIdx.y * 64, bn = blockIdx.x * 64;
  int kz = blockIdx.z;
  f32x4 acc[2][2] = {};
  int lrow = tid >> 2;
  int lcg  = (tid & 3) * 8;
  const size_t aoff = (size_t)(bm + lrow) * Kstride + (size_t)kz * K + lcg;
  const size_t boff = (size_t)(bn + lrow) * Kstride + (size_t)kz * K + lcg;
  int fr = lane & 15, kg = (lane >> 4) * 8;
  short8 pa = *(const short8*)&A[aoff];
  short8 pb = *(const short8*)&W[boff];
  *(short8*)&As[0][lrow*40 + lcg] = pa;
  *(short8*)&Bs[0][lrow*40 + lcg] = pb;
  __syncthreads();
  int cur = 0;
  for (int k0 = 0; k0 < K; k0 += 32) {
    bool hn = (k0 + 32) < K;
    if (hn) {
      pa = *(const short8*)&A[aoff + k0 + 32];
      pb = *(const short8*)&W[boff + k0 + 32];
    }
    short8 af0 = *(const short8*)&As[cur][(wr*32 +      fr)*40 + kg];
    short8 af1 = *(const short8*)&As[cur][(wr*32 + 16 + fr)*40 + kg];
    short8 bf0 = *(const short8*)&Bs[cur][(wc*32 +      fr)*40 + kg];
    short8 bf1 = *(const short8*)&Bs[cur][(wc*32 + 16 + fr)*40 + kg];
    acc[0][0] = __builtin_amdgcn_mfma_f32_16x16x32_bf16(af0, bf0, acc[0][0], 0,0,0);
    acc[0][1] = __builtin_amdgcn_mfma_f32_16x16x32_bf16(af0, bf1, acc[0][1], 0,0,0);
    acc[1][0] = __builtin_amdgcn_mfma_f32_16x16x32_bf16(af1, bf0, acc[1][0], 0,0,0);
    acc[1][1] = __builtin_amdgcn_mfma_f32_16x16x32_bf16(af1, bf1, acc[1][1], 0,0,0);
    if (hn) {
      *(short8*)&As[cur^1][lrow*40 + lcg] = pa;
      *(short8*)&Bs[cur^1][lrow*40 + lcg] = pb;
    }
    __syncthreads();
    cur ^= 1;
  }
  int rbase = (lane >> 4) * 4;
  #pragma unroll
  for (int m = 0; m < 2; m++) {
    #pragma unroll
    for (int n = 0; n < 2; n++) {
      int col = bn + wc*32 + n*16 + (lane & 15);
      float bc = (OUTMODE == 3) ? 0.f : bias[col];
      #pragma unroll
      for (int r = 0; r < 4; r++) {
        int row = bm + wr*32 + m*16 + rbase + r;
        float vv = acc[m][n][r] + bc;
        if (RELU) vv = fmaxf(vv, 0.f);
        if (OUTMODE == 2) {
          int which = col >> 9, hh = (col >> 6) & 7, dd = col & 63;
          size_t idx = ((((size_t)which*BATCH_N + (row & 1))*H_N + hh)*S_LEN + (row >> 1))*DK_N + dd;
          Cb[idx] = f2b(vv);
        } else if (OUTMODE == 3) {
          Cf[(size_t)kz*MN_PART + (size_t)row*N + col] = vv;
        } else {
          size_t idx = (size_t)row * N + col;
          if (RESID) vv += resid[idx];
          if (OUTMODE == 1) Cb[idx] = f2b(vv);
          else              Cf[idx] = vv;
        }
      }
    }
  }
}

// ---- FFN2 split-K combine: out = sum(partials) + bias + resid (f32) ----
__global__ __launch_bounds__(256) void ffn2_combine(
    const float* __restrict__ part, const float* __restrict__ bias,
    const float* __restrict__ resid, float* __restrict__ out)
{
  int i = (blockIdx.x*256 + threadIdx.x)*4;
  float4 a = *(const float4*)(part + i);
  float4 b = *(const float4*)(part + MN_PART + i);
  float4 c = *(const float4*)(part + 2*MN_PART + i);
  float4 d = *(const float4*)(part + 3*MN_PART + i);
  float4 bs = *(const float4*)(bias + (i & 511));
  float4 rs = *(const float4*)(resid + i);
  float4 o;
  o.x = a.x + b.x + c.x + d.x + bs.x + rs.x;
  o.y = a.y + b.y + c.y + d.y + bs.y + rs.y;
  o.z = a.z + b.z + c.z + d.z + bs.z + rs.z;
  o.w = a.w + b.w + c.w + d.w + bs.w + rs.w;
  *(float4*)(out + i) = o;
}

// ---- 128x128-tile GEMM, global_load_lds staging (FFN1) ----
template<int RELU, int OUTMODE, int VSTART>
__global__ __launch_bounds__(256) void gemm128(
    const unsigned short* __restrict__ A, const unsigned short* __restrict__ W,
    const float* __restrict__ bias, unsigned short* __restrict__ Cb,
    int M, int N, int K)
{
  __shared__ unsigned short As[128*32];
  __shared__ unsigned short Bs[128*32];
  int tid = threadIdx.x, lane = tid & 63, w = tid >> 6;
  int bm = blockIdx.y * 128, bn = blockIdx.x * 128;
  int fr = lane & 15, hi = lane >> 4;
  int kg8 = hi*8, rg = hi*4;
  int wm = (w >> 1) * 64, wn = (w & 1) * 64;
  f32x4 acc[4][4] = {};
  const unsigned short* ga0 = A + (size_t)(bm +      (tid>>2))*K + (tid&3)*8;
  const unsigned short* ga1 = A + (size_t)(bm + 64 + (tid>>2))*K + (tid&3)*8;
  const unsigned short* gb0 = W + (size_t)(bn +      (tid>>2))*K + (tid&3)*8;
  const unsigned short* gb1 = W + (size_t)(bn + 64 + (tid>>2))*K + (tid&3)*8;
  unsigned short* lA0 = &As[tid*8];
  unsigned short* lA1 = &As[2048 + tid*8];
  unsigned short* lB0 = &Bs[tid*8];
  unsigned short* lB1 = &Bs[2048 + tid*8];
  for (int k0 = 0; k0 < K; k0 += 32) {
    gl_lds16(ga0 + k0, lA0);
    gl_lds16(ga1 + k0, lA1);
    gl_lds16(gb0 + k0, lB0);
    gl_lds16(gb1 + k0, lB1);
    __syncthreads();
    short8 af[4], bf[4];
    #pragma unroll
    for (int m = 0; m < 4; m++) af[m] = *(const short8*)&As[(wm + m*16 + fr)*32 + kg8];
    #pragma unroll
    for (int n = 0; n < 4; n++) bf[n] = *(const short8*)&Bs[(wn + n*16 + fr)*32 + kg8];
    __builtin_amdgcn_s_setprio(1);
    #pragma unroll
    for (int m = 0; m < 4; m++)
      #pragma unroll
      for (int n = 0; n < 4; n++)
        acc[m][n] = __builtin_amdgcn_mfma_f32_16x16x32_bf16(af[m], bf[n], acc[m][n], 0,0,0);
    __builtin_amdgcn_s_setprio(0);
    __syncthreads();
  }
  #pragma unroll
  for (int m = 0; m < 4; m++) {
    #pragma unroll
    for (int n = 0; n < 4; n++) {
      int col = bn + wn + n*16 + fr;
      float bc = bias[col];
      #pragma unroll
      for (int r = 0; r < 4; r++) {
        int row = bm + wm + m*16 + rg + r;
        float vv = acc[m][n][r] + bc;
        if (RELU) vv = fmaxf(vv, 0.f);
        if (OUTMODE == 2) {
          int which = col >> 9, hh = (col >> 6) & 7, dd = col & 63;
          int srow = row >> 1, bb = row & 1;
          size_t idx;
          if (which >= VSTART)
            idx = (size_t)which*QSZ + (((size_t)bb*H_N + hh)*DK_N + dd)*S_LEN + srow;
          else
            idx = (size_t)which*QSZ + (((size_t)bb*H_N + hh)*S_LEN + srow)*DK_N + dd;
          Cb[idx] = f2b(vv);
        } else {
          Cb[(size_t)row * N + col] = f2b(vv);
        }
      }
    }
  }
}

// ---- merged self-QKV (12 col-tiles) + cross-KV (8 col-tiles) GEMM ----
// bx<12: A=nx_bf W=w_sa -> qkv_sa (VSTART=2). bx>=12: A=mem_bf W=ca_K -> kv_ca (VSTART=1).
__global__ __launch_bounds__(256) void gemm128_dual(
    const unsigned short* __restrict__ A0, const unsigned short* __restrict__ W0,
    const float* __restrict__ bias0, unsigned short* __restrict__ C0,
    const unsigned short* __restrict__ A1, const unsigned short* __restrict__ W1,
    const float* __restrict__ bias1, unsigned short* __restrict__ C1)
{
  const int K = 512;
  int bx = blockIdx.x;
  const unsigned short* A; const unsigned short* W; const float* bias;
  unsigned short* Cb; int bn, vs;
  if (bx < 12) { A = A0; W = W0; bias = bias0; Cb = C0; bn = bx*128;      vs = 2; }
  else         { A = A1; W = W1; bias = bias1; Cb = C1; bn = (bx-12)*128; vs = 1; }
  __shared__ unsigned short As[128*32];
  __shared__ unsigned short Bs[128*32];
  int tid = threadIdx.x, lane = tid & 63, w = tid >> 6;
  int bm = blockIdx.y * 128;
  int fr = lane & 15, hi = lane >> 4;
  int kg8 = hi*8, rg = hi*4;
  int wm = (w >> 1) * 64, wn = (w & 1) * 64;
  f32x4 acc[4][4] = {};
  const unsigned short* ga0 = A + (size_t)(bm +      (tid>>2))*K + (tid&3)*8;
  const unsigned short* ga1 = A + (size_t)(bm + 64 + (tid>>2))*K + (tid&3)*8;
  const unsigned short* gb0 = W + (size_t)(bn +      (tid>>2))*K + (tid&3)*8;
  const unsigned short* gb1 = W + (size_t)(bn + 64 + (tid>>2))*K + (tid&3)*8;
  unsigned short* lA0 = &As[tid*8];
  unsigned short* lA1 = &As[2048 + tid*8];
  unsigned short* lB0 = &Bs[tid*8];
  unsigned short* lB1 = &Bs[2048 + tid*8];
  for (int k0 = 0; k0 < K; k0 += 32) {
    gl_lds16(ga0 + k0, lA0);
    gl_lds16(ga1 + k0, lA1);
    gl_lds16(gb0 + k0, lB0);
    gl_lds16(gb1 + k0, lB1);
    __syncthreads();
    short8 af[4], bf[4];
    #pragma unroll
    for (int m = 0; m < 4; m++) af[m] = *(const short8*)&As[(wm + m*16 + fr)*32 + kg8];
    #pragma unroll
    for (int n = 0; n < 4; n++) bf[n] = *(const short8*)&Bs[(wn + n*16 + fr)*32 + kg8];
    __builtin_amdgcn_s_setprio(1);
    #pragma unroll
    for (int m = 0; m < 4; m++)
      #pragma unroll
      for (int n = 0; n < 4; n++)
        acc[m][n] = __builtin_amdgcn_mfma_f32_16x16x32_bf16(af[m], bf[n], acc[m][n], 0,0,0);
    __builtin_amdgcn_s_setprio(0);
    __syncthreads();
  }
  #pragma unroll
  for (int m = 0; m < 4; m++) {
    #pragma unroll
    for (int n = 0; n < 4; n++) {
      int col = bn + wn + n*16 + fr;
      float bc = bias[col];
      #pragma unroll
      for (int r = 0; r < 4; r++) {
        int row = bm + wm + m*16 + rg + r;
        float vv = acc[m][n][r] + bc;
        int which = col >> 9, hh = (col >> 6) & 7, dd = col & 63;
        int srow = row >> 1, bb = row & 1;
        size_t idx;
        if (which >= vs)
          idx = (size_t)which*QSZ + (((size_t)bb*H_N + hh)*DK_N + dd)*S_LEN + srow;
        else
          idx = (size_t)which*QSZ + (((size_t)bb*H_N + hh)*S_LEN + srow)*DK_N + dd;
        Cb[idx] = f2b(vv);
      }
    }
  }
}

// ---- 32x32-MFMA flash attention v3: 128 q-rows/block, wave owns full rows ----
template<int MODE>
__global__ __launch_bounds__(256, 4) void attn3(
    const unsigned short* __restrict__ qg, const unsigned short* __restrict__ kpl,
    const unsigned short* __restrict__ vtpl, const unsigned long long* __restrict__ bm,
    unsigned short* __restrict__ opart, float* __restrict__ lpart)
{
  __shared__ unsigned short SM[2*64*72];   // Ks | Vt
  unsigned short* Ks = SM;
  unsigned short* Vt = SM + 64*72;
  int tid = threadIdx.x;
  int lane = tid & 63, w = tid >> 6;
  int l31 = lane & 31, hi5 = lane >> 5;
  int bid = blockIdx.x;
  int p = bid & 15, u = bid >> 4;
  int qtile = u >> 2, range = u & 3;
  int h = p & 7, b = p >> 3;
  const size_t sbase = (size_t)(b*H_N + h) * S_LEN;
  int kt0 = range*8, kt1 = kt0 + 7;
  if (MODE == 0) {
    int ktmax_tile = qtile*2 + 1;
    if (kt0 > ktmax_tile) {           // inactive: zero partial slice, exit
      int zr = tid >> 1, zc = (tid & 1) * 32;
      short8 z = {};
      size_t zb = (size_t)range*QSZ + (sbase + (size_t)qtile*128 + zr)*DK_N + zc;
      *(short8*)&opart[zb]      = z;
      *(short8*)&opart[zb + 8]  = z;
      *(short8*)&opart[zb + 16] = z;
      *(short8*)&opart[zb + 24] = z;
      if (tid < 128) lpart[range*32768 + (int)sbase + qtile*128 + tid] = 0.f;
      return;
    }
    if (kt1 > ktmax_tile) kt1 = ktmax_tile;
  }
  int qrow = qtile*128 + w*32 + l31;
  short8 qf[4];
  #pragma unroll
  for (int km = 0; km < 4; km++)
    qf[km] = *(const short8*)&qg[(sbase + qrow)*DK_N + km*16 + hi5*8];

  int sr = tid >> 2, sc = (tid & 3) * 16;
  const unsigned short* kbase = &kpl[(sbase + sr)*DK_N + sc];
  const unsigned short* vbase = &vtpl[((size_t)(b*H_N + h)*DK_N + sr)*S_LEN + sc];

  f32x16 oa0 = {}, oa1 = {};
  float lp = 0.f;
  for (int kt = kt0; kt <= kt1; kt++) {
    __syncthreads();
    {
      const unsigned short* kg = kbase + (size_t)kt*64*DK_N;
      const unsigned short* vg = vbase + kt*64;
      *(short8*)&Ks[sr*72 + sc]     = *(const short8*)kg;
      *(short8*)&Ks[sr*72 + sc + 8] = *(const short8*)(kg + 8);
      *(short8*)&Vt[sr*72 + sc]     = *(const short8*)vg;
      *(short8*)&Vt[sr*72 + sc + 8] = *(const short8*)(vg + 8);
    }
    __syncthreads();
    #pragma unroll
    for (int kb = 0; kb < 2; kb++) {
      f32x16 sa = {};
      __builtin_amdgcn_s_setprio(1);
      #pragma unroll
      for (int km = 0; km < 4; km++) {
        short8 kf = *(const short8*)&Ks[(kb*32 + l31)*72 + km*16 + hi5*8];
        sa = __builtin_amdgcn_mfma_f32_32x32x16_bf16(kf, qf[km], sa, 0, 0, 0);
      }
      __builtin_amdgcn_s_setprio(0);
      unsigned mlo = 0;
      if (MODE == 1) mlo = (unsigned)(bm[b*32 + kt] >> (kb*32 + 4*hi5));
      float pv[16];
      float psum = 0.f;
      #pragma unroll
      for (int r = 0; r < 16; r++) {
        const int pos = (r & 3) + 8*(r >> 2);
        float e = __expf(sa[r] * 0.125f);
        bool dead;
        if (MODE == 0) dead = (kt*64 + kb*32 + 4*hi5 + pos) > qrow;
        else           dead = ((mlo >> pos) & 1u) != 0u;
        e = dead ? 0.f : e;
        pv[r] = e;
        psum += e;
      }
      lp += psum;
      unsigned pk[8];
      #pragma unroll
      for (int i = 0; i < 8; i++)
        asm("v_cvt_pk_bf16_f32 %0, %1, %2" : "=v"(pk[i]) : "v"(pv[2*i]), "v"(pv[2*i+1]));
      asm("v_permlane32_swap_b32 %0, %1" : "+v"(pk[0]), "+v"(pk[2]));
      asm("v_permlane32_swap_b32 %0, %1" : "+v"(pk[1]), "+v"(pk[3]));
      asm("v_permlane32_swap_b32 %0, %1" : "+v"(pk[4]), "+v"(pk[6]));
      asm("v_permlane32_swap_b32 %0, %1" : "+v"(pk[5]), "+v"(pk[7]));
      uint4v f0v, f1v;
      f0v.x = pk[0]; f0v.y = pk[1]; f0v.z = pk[2]; f0v.w = pk[3];
      f1v.x = pk[4]; f1v.y = pk[5]; f1v.z = pk[6]; f1v.w = pk[7];
      short8 pf0 = *(short8*)&f0v;
      short8 pf1 = *(short8*)&f1v;
      __builtin_amdgcn_s_setprio(1);
      {
        short8 v00 = *(const short8*)&Vt[(     l31)*72 + kb*32 +      hi5*8];
        short8 v01 = *(const short8*)&Vt[(     l31)*72 + kb*32 + 16 + hi5*8];
        oa0 = __builtin_amdgcn_mfma_f32_32x32x16_bf16(pf0, v00, oa0, 0, 0, 0);
        oa0 = __builtin_amdgcn_mfma_f32_32x32x16_bf16(pf1, v01, oa0, 0, 0, 0);
        short8 v10 = *(const short8*)&Vt[(32 + l31)*72 + kb*32 +      hi5*8];
        short8 v11 = *(const short8*)&Vt[(32 + l31)*72 + kb*32 + 16 + hi5*8];
        oa1 = __builtin_amdgcn_mfma_f32_32x32x16_bf16(pf0, v10, oa1, 0, 0, 0);
        oa1 = __builtin_amdgcn_mfma_f32_32x32x16_bf16(pf1, v11, oa1, 0, 0, 0);
      }
      __builtin_amdgcn_s_setprio(0);
    }
  }
  float lptot = lp + __shfl_xor(lp, 32);
  if (lane < 32)
    lpart[range*32768 + (int)sbase + qtile*128 + w*32 + l31] = lptot;
  #pragma unroll
  for (int r = 0; r < 16; r++) {
    const int pos = (r & 3) + 8*(r >> 2);
    int qr = qtile*128 + w*32 + pos + 4*hi5;
    size_t obase = (size_t)range*QSZ + (sbase + (size_t)qr)*DK_N;
    opart[obase + l31]      = f2b(oa0[r]);
    opart[obase + 32 + l31] = f2b(oa1[r]);
  }
}

// ---- merge the four key-range partials: o = sum(O_r) / sum(l_r) ----
__global__ __launch_bounds__(256) void attn_combine4(
    const unsigned short* __restrict__ op, const float* __restrict__ lp,
    unsigned short* __restrict__ o)
{
  int t = blockIdx.x*256 + threadIdx.x;
  int f = t*8;
  int col = f & 511, row = f >> 9;
  int h = col >> 6, d = col & 63, s = row >> 1, b = row & 1;
  size_t pr = ((size_t)b*H_N + h)*S_LEN + s;
  size_t base = pr*DK_N + d;
  float acc[8] = {0.f,0.f,0.f,0.f,0.f,0.f,0.f,0.f};
  float l = 0.f;
  #pragma unroll
  for (int r = 0; r < 4; r++) {
    short8 a = *(const short8*)&op[(size_t)r*QSZ + base];
    #pragma unroll
    for (int i = 0; i < 8; i++) acc[i] += b2f((unsigned short)a[i]);
    l += lp[r*32768 + (int)pr];
  }
  float inv = 1.f / l;
  short8 r8;
  #pragma unroll
  for (int i = 0; i < 8; i++) r8[i] = (short)f2b(acc[i] * inv);
  *(short8*)&o[(size_t)row*DM + col] = r8;
}

extern "C" void kernel_launch(void* const* d_in, const int* in_sizes, int n_in,
                              void* d_out, int out_size, void* d_ws, size_t ws_size,
                              hipStream_t stream) {
  const float* x       = (const float*)d_in[0];
  const float* memory  = (const float*)d_in[1];
  const int*   memmask = (const int*)d_in[3];
  const float* sa_W = (const float*)d_in[4];
  const float* sa_b = (const float*)d_in[5];
  const float* ca_W = (const float*)d_in[6];
  const float* ca_b = (const float*)d_in[7];
  const float* w1   = (const float*)d_in[8];
  const float* b1   = (const float*)d_in[9];
  const float* w2   = (const float*)d_in[10];
  const float* b2   = (const float*)d_in[11];
  const float* ln_g = (const float*)d_in[12];
  const float* ln_b = (const float*)d_in[13];
  float* out = (float*)d_out;

  char* ws = (char*)d_ws;
  float*          xcur   = (float*)ws;                              // 0..8 MB
  unsigned short* nx_bf  = (unsigned short*)(ws + (8u<<20));        // 8..12 MB
  unsigned short* qkv_sa = (unsigned short*)(ws + (12u<<20));       // 12..24 MB
  unsigned short* q_ca   = (unsigned short*)(ws + (24u<<20));       // 24..28 MB
  unsigned short* kv_ca  = (unsigned short*)(ws + (28u<<20));       // 28..36 MB
  unsigned short* o_bf   = (unsigned short*)(ws + (36u<<20));       // 36..40 MB
  unsigned short* mem_bf = (unsigned short*)(ws + (40u<<20));       // 40..44 MB
  unsigned short* h_bf   = (unsigned short*)(ws + (44u<<20));       // 44..60 MB (FFN hidden)
  unsigned short* opart  = (unsigned short*)(ws + (44u<<20));       // 44..60 MB (attn phases)
  float*          fpart  = (float*)(ws + (12u<<20));                // 12..44 MB (FFN2 split-K, dead bufs)
  float*          lpart  = (float*)(ws + (60u<<20));                // 60..60.5 MB
  unsigned long long* bmsk = (unsigned long long*)(ws + (60u<<20) + (1u<<19)); // 512 B
  unsigned short* w_sa   = (unsigned short*)(ws + (61u<<20));       // weights bf16
  unsigned short* w_ca   = w_sa + 4*512*512;
  unsigned short* w_f1   = w_ca + 4*512*512;
  unsigned short* w_f2   = w_f1 + 2048*512;

  dim3 blk(256);
  dim3 g512 (512/64,  4096/64);
  dim3 gdual(20, 4096/128);
  dim3 q128_2048(2048/128, 4096/128);
  dim3 gsplitk(512/64, 4096/64, 4);

  // prep: casts + maskpack + LN1
  prep_kernel<<<7169, blk, 0, stream>>>(sa_W, ca_W, w1, w2, memory, memmask,
                                        x, ln_g, ln_b,
                                        w_sa, w_ca, w_f1, w_f2, mem_bf, bmsk, nx_bf);

  // ---- self-attention block (+ cross K/V GEMM merged) ----
  gemm128_dual<<<gdual, blk, 0, stream>>>(nx_bf, w_sa, sa_b, qkv_sa,
                                          mem_bf, w_ca + 262144, ca_b + 512, kv_ca);
  attn3<0><<<1024, blk, 0, stream>>>(qkv_sa, qkv_sa + QSZ, qkv_sa + 2*QSZ, nullptr, opart, lpart);
  attn_combine4<<<1024, blk, 0, stream>>>(opart, lpart, o_bf);
  gemm_bt<0,0,1><<<g512, blk, 0, stream>>>(o_bf, w_sa + 3*262144, sa_b + 1536, x, xcur, nullptr, 4096, 512, 512, 512);

  // ---- cross-attention block ----
  ln4_kernel<<<1024, blk, 0, stream>>>(xcur, ln_g + 512, ln_b + 512, nx_bf);
  gemm_bt<0,2,0><<<g512, blk, 0, stream>>>(nx_bf, w_ca, ca_b, nullptr, nullptr, q_ca, 4096, 512, 512, 512);
  attn3<1><<<1024, blk, 0, stream>>>(q_ca, kv_ca, kv_ca + QSZ, bmsk, opart, lpart);
  attn_combine4<<<1024, blk, 0, stream>>>(opart, lpart, o_bf);
  gemm_bt<0,0,1><<<g512, blk, 0, stream>>>(o_bf, w_ca + 3*262144, ca_b + 1536, xcur, xcur, nullptr, 4096, 512, 512, 512);

  // ---- FFN block ----
  ln4_kernel<<<1024, blk, 0, stream>>>(xcur, ln_g + 1024, ln_b + 1024, nx_bf);
  gemm128<1,1,0><<<q128_2048, blk, 0, stream>>>(nx_bf, w_f1, b1, h_bf, 4096, 2048, 512);
  gemm_bt<0,3,0><<<gsplitk, blk, 0, stream>>>(h_bf, w_f2, nullptr, nullptr, fpart, nullptr, 4096, 512, 512, 2048);
  ffn2_combine<<<2048, blk, 0, stream>>>(fpart, b2, xcur, out);
}